// Round 5
// baseline (738.375 us; speedup 1.0000x reference)
//
#include <hip/hip_runtime.h>

#define BS 256       // 4 waves/block; each wave owns its 64 rows + private LDS chunk. Zero barriers.
#define NFEAT 121
#define CHUNK 16     // rows per flush chunk
#define WA 64        // phase-A width: cols [0,64)  = f0..f7
#define WB 57        // phase-B width: cols [64,121) = f8..f10
#define SA4 17       // phase-A LDS row stride, in float4 (68 floats; mr*68%32=mr*4 -> 2-way, free)
#define SB4 15       // phase-B LDS row stride, in float4 (60 floats; mr*60%32=28mr -> 2-way, free)

// Two-phase register split: phase A keeps f[0..63] in regs (peak ~85 VGPR incl. overhead,
// no scratch spill -- Round 4's f[121] forced ~50 spilled floats/lane, VGPR_Count=76<121).
// Each phase flushes through a per-wave 16-row LDS transpose chunk -> coalesced stores.

__device__ __forceinline__ float dot3(const float* __restrict__ c, float x, float y, float z) {
    return fmaf(c[2], z, fmaf(c[1], y, c[0] * x));
}

// out[j] = sum_a prev[a] * dot3(cob[j,3a..], f1); fully unrolled, static indices only.
template<int LL>
__device__ __forceinline__ void step_l(const float* __restrict__ cob,
                                       const float* prevArr, float* outArr,
                                       float f1x, float f1y, float f1z) {
    constexpr int IN  = 2 * LL - 1;
    constexpr int OUT = 2 * LL + 1;
    #pragma unroll
    for (int j = 0; j < OUT; ++j) {
        const float* __restrict__ crow = cob + j * (3 * IN);  // wave-uniform -> s_load
        float acc = 0.f;
        #pragma unroll
        for (int a = 0; a < IN; ++a)
            acc = fmaf(prevArr[a], dot3(crow + 3 * a, f1x, f1y, f1z), acc);
        outArr[j] = acc;
    }
}

__global__ __launch_bounds__(BS) void harmonic_kernel(
    const float* __restrict__ points,
    const float* __restrict__ cob1,  const float* __restrict__ cob2,
    const float* __restrict__ cob3,  const float* __restrict__ cob4,
    const float* __restrict__ cob5,  const float* __restrict__ cob6,
    const float* __restrict__ cob7,  const float* __restrict__ cob8,
    const float* __restrict__ cob9,  const float* __restrict__ cob10,
    float* __restrict__ out, int N) {
    // 4 waves x (16 rows x 17 float4) = 17,408 B
    __shared__ float4 sbuf4[BS / 64][CHUNK * SA4];

    const int t    = threadIdx.x;
    const int lane = t & 63;
    const int w    = t >> 6;
    const long long wbase = (long long)blockIdx.x * BS + ((long long)w << 6);
    const long long p     = wbase + lane;
    const bool active = p < (long long)N;
    long long nv = (long long)N - wbase;
    const int wrows = nv >= 64 ? 64 : (nv > 0 ? (int)nv : 0);

    float px = 0.f, py = 0.f, pz = 0.f;
    if (active) {
        px = points[p * 3 + 0];
        py = points[p * 3 + 1];
        pz = points[p * 3 + 2];
    }

    const float f1x = dot3(cob1 + 0, px, py, pz);
    const float f1y = dot3(cob1 + 3, px, py, pz);
    const float f1z = dot3(cob1 + 6, px, py, pz);

    float4* wb4 = &sbuf4[w][0];          // this wave's chunk buffer (no __restrict__:
    float*  wbf = (float*)wb4;           // write/read aliasing must stay visible)
    float* __restrict__ outw = out + wbase * NFEAT;

    const int myc = lane >> 4;           // which chunk this lane's row belongs to
    const int mr  = lane & 15;           // row within chunk

    // ================= Phase A: f0..f7 -> regs fA[0..63], flush cols [0,64) ============
    float fA[WA];
    fA[0] = 1.f; fA[1] = f1x; fA[2] = f1y; fA[3] = f1z;
    step_l<2>(cob2, fA + 1,  fA + 4,  f1x, f1y, f1z);
    step_l<3>(cob3, fA + 4,  fA + 9,  f1x, f1y, f1z);
    step_l<4>(cob4, fA + 9,  fA + 16, f1x, f1y, f1z);
    step_l<5>(cob5, fA + 16, fA + 25, f1x, f1y, f1z);
    step_l<6>(cob6, fA + 25, fA + 36, f1x, f1y, f1z);
    step_l<7>(cob7, fA + 36, fA + 49, f1x, f1y, f1z);

    if (wrows == 64) {                   // bulk path
        for (int c = 0; c < 4; ++c) {
            if (myc == c) {              // stage: 16 x ds_write_b128, 16B-aligned
                #pragma unroll
                for (int k = 0; k < 16; ++k)
                    wb4[mr * SA4 + k] = make_float4(fA[4*k], fA[4*k+1], fA[4*k+2], fA[4*k+3]);
            }
            // drain: row per iteration, 64 lanes -> 256 B contiguous burst
            #pragma unroll
            for (int r = 0; r < 16; ++r)
                outw[(c * 16 + r) * NFEAT + lane] = wbf[r * (4 * SA4) + lane];
        }
    } else if (wrows > 0) {              // tail block
        for (int c = 0; c < 4 && c * 16 < wrows; ++c) {
            if (myc == c) {
                #pragma unroll
                for (int k = 0; k < 16; ++k)
                    wb4[mr * SA4 + k] = make_float4(fA[4*k], fA[4*k+1], fA[4*k+2], fA[4*k+3]);
            }
            #pragma unroll
            for (int r = 0; r < 16; ++r)
                if (c * 16 + r < wrows)
                    outw[(c * 16 + r) * NFEAT + lane] = wbf[r * (4 * SA4) + lane];
        }
    }

    // ================= Phase B: f8..f10 -> regs fB[0..56], flush cols [64,121) =========
    // prev for f8 is fA[49..63]; the rest of fA is dead -> registers freed.
    float fB[WB];
    step_l<8> (cob8,  fA + 49, fB + 0,  f1x, f1y, f1z);
    step_l<9> (cob9,  fB + 0,  fB + 17, f1x, f1y, f1z);
    step_l<10>(cob10, fB + 17, fB + 36, f1x, f1y, f1z);

    if (wrows == 64) {
        for (int c = 0; c < 4; ++c) {
            if (myc == c) {              // 14 x ds_write_b128 + 1 scalar
                #pragma unroll
                for (int k = 0; k < 14; ++k)
                    wb4[mr * SB4 + k] = make_float4(fB[4*k], fB[4*k+1], fB[4*k+2], fB[4*k+3]);
                wbf[mr * (4 * SB4) + 56] = fB[56];
            }
            if (lane < WB) {             // 57 lanes -> 228 B contiguous burst per row
                #pragma unroll
                for (int r = 0; r < 16; ++r)
                    outw[(c * 16 + r) * NFEAT + WA + lane] = wbf[r * (4 * SB4) + lane];
            }
        }
    } else if (wrows > 0) {
        for (int c = 0; c < 4 && c * 16 < wrows; ++c) {
            if (myc == c) {
                #pragma unroll
                for (int k = 0; k < 14; ++k)
                    wb4[mr * SB4 + k] = make_float4(fB[4*k], fB[4*k+1], fB[4*k+2], fB[4*k+3]);
                wbf[mr * (4 * SB4) + 56] = fB[56];
            }
            if (lane < WB) {
                #pragma unroll
                for (int r = 0; r < 16; ++r)
                    if (c * 16 + r < wrows)
                        outw[(c * 16 + r) * NFEAT + WA + lane] = wbf[r * (4 * SB4) + lane];
            }
        }
    }
}

extern "C" void kernel_launch(void* const* d_in, const int* in_sizes, int n_in,
                              void* d_out, int out_size, void* d_ws, size_t ws_size,
                              hipStream_t stream) {
    const float* points = (const float*)d_in[0];
    const float* cob[10];
    for (int i = 0; i < 10; ++i) cob[i] = (const float*)d_in[1 + i];
    float* out = (float*)d_out;
    const int N = in_sizes[0] / 3;

    const int grid = (N + BS - 1) / BS;
    harmonic_kernel<<<grid, BS, 0, stream>>>(
        points,
        cob[0], cob[1], cob[2], cob[3], cob[4],
        cob[5], cob[6], cob[7], cob[8], cob[9],
        out, N);
}